// Round 1
// baseline (772.128 us; speedup 1.0000x reference)
//
#include <hip/hip_runtime.h>

#define B  8
#define NV 4096
#define NE 32768
#define D  128
#define KE 512   // De + 2*Dv + Du
#define KN 384   // Dep + Dv + Du
#define KG 384   // Dep + Dvp + Du

// ---------------------------------------------------------------------------
// Edge block: edges_p = relu(concat(edges, nodes[recv], nodes[send], u) @ W_e + b_e)
// Also: masked atomic scatter-add into e2v[recv], block-reduced atomics into e2u.
// 32 edges per block, 256 threads (8 groups of 32 lanes).
// ---------------------------------------------------------------------------
__global__ __launch_bounds__(256) void edge_kernel(
    const float* __restrict__ nodes,      // (B,NV,D)
    const float* __restrict__ edges,      // (B,NE,D)
    const float* __restrict__ gu,         // (B,D)
    const int*   __restrict__ edge_rs,    // (B,NE,2)
    const int*   __restrict__ edge_masks, // (B,NE)
    const float* __restrict__ W_edge,     // (KE,D) row-major
    const float* __restrict__ b_edge,     // (D)
    float* __restrict__ edges_p,          // (B,NE,D)
    float* __restrict__ e2v,              // (B,NV,D) accum
    float* __restrict__ e2u)              // (B,D)    accum
{
    __shared__ float in_lds[32][KE];      // 64 KB exactly

    const int b   = blockIdx.y;
    const int e0  = blockIdx.x * 32;
    const int tid = threadIdx.x;
    const int tx  = tid & 31;             // lane within group -> output cols
    const int ty  = tid >> 5;             // group 0..7        -> edges
    const int j0  = tx * 4;

    // ---- stage concat input, transposed-by-edge rows, coalesced float4 ----
    #pragma unroll
    for (int i = 0; i < 4; ++i) {
        const int    el = ty + 8 * i;            // local edge 0..31
        const size_t eb = (size_t)b * NE + e0 + el;
        const int2   rs = ((const int2*)edge_rs)[eb];   // broadcast load
        const float4 ev = *(const float4*)(edges + eb * D + j0);
        const float4 rv = *(const float4*)(nodes + ((size_t)b * NV + rs.x) * D + j0);
        const float4 sv = *(const float4*)(nodes + ((size_t)b * NV + rs.y) * D + j0);
        const float4 uv = *(const float4*)(gu + (size_t)b * D + j0);
        *(float4*)(&in_lds[el][  0 + j0]) = ev;
        *(float4*)(&in_lds[el][128 + j0]) = rv;
        *(float4*)(&in_lds[el][256 + j0]) = sv;
        *(float4*)(&in_lds[el][384 + j0]) = uv;
    }
    __syncthreads();

    // ---- GEMM: 4 edges x 4 cols per thread ----
    float acc[4][4] = {};
    #pragma unroll 4
    for (int k = 0; k < KE; ++k) {
        const float4 w = *(const float4*)(W_edge + (size_t)k * D + j0);
        #pragma unroll
        for (int i = 0; i < 4; ++i) {
            const float x = in_lds[ty + 8 * i][k];   // wave-broadcast read
            acc[i][0] += x * w.x;
            acc[i][1] += x * w.y;
            acc[i][2] += x * w.z;
            acc[i][3] += x * w.w;
        }
    }

    // ---- epilogue: bias + relu, store, scatter, e2u partial ----
    const float4 bb = *(const float4*)(b_edge + j0);
    float4 psum = make_float4(0.f, 0.f, 0.f, 0.f);
    #pragma unroll
    for (int i = 0; i < 4; ++i) {
        const int    el = ty + 8 * i;
        const size_t eb = (size_t)b * NE + e0 + el;
        float4 o;
        o.x = fmaxf(acc[i][0] + bb.x, 0.f);
        o.y = fmaxf(acc[i][1] + bb.y, 0.f);
        o.z = fmaxf(acc[i][2] + bb.z, 0.f);
        o.w = fmaxf(acc[i][3] + bb.w, 0.f);
        *(float4*)(edges_p + eb * D + j0) = o;
        psum.x += o.x; psum.y += o.y; psum.z += o.z; psum.w += o.w;

        const int m = edge_masks[eb];
        if (m) {
            const int r = ((const int2*)edge_rs)[eb].x;
            float* dst = e2v + ((size_t)b * NV + r) * D + j0;
            atomicAdd(dst + 0, o.x);
            atomicAdd(dst + 1, o.y);
            atomicAdd(dst + 2, o.z);
            atomicAdd(dst + 3, o.w);
        }
    }

    // block-reduce psum over ty groups (reuse in_lds), one atomic per col
    __syncthreads();                       // everyone done reading in_lds
    float* red = &in_lds[0][0];            // [8][128]
    *(float4*)(red + ty * 128 + j0) = psum;
    __syncthreads();
    if (tid < 128) {
        float s = 0.f;
        #pragma unroll
        for (int t = 0; t < 8; ++t) s += red[t * 128 + tid];
        atomicAdd(&e2u[(size_t)b * D + tid], s);
    }
}

// ---------------------------------------------------------------------------
// Node block: nodes_p = relu(concat(e2v, nodes, u) @ W_n + b_n); v2u accum.
// ---------------------------------------------------------------------------
__global__ __launch_bounds__(256) void node_kernel(
    const float* __restrict__ nodes,
    const float* __restrict__ gu,
    const float* __restrict__ e2v,
    const float* __restrict__ W_node,     // (KN,D)
    const float* __restrict__ b_node,
    float* __restrict__ nodes_p,          // (B,NV,D)
    float* __restrict__ v2u)              // (B,D) accum
{
    __shared__ float in_lds[32][KN];      // 48 KB

    const int b   = blockIdx.y;
    const int n0  = blockIdx.x * 32;
    const int tid = threadIdx.x;
    const int tx  = tid & 31;
    const int ty  = tid >> 5;
    const int j0  = tx * 4;

    #pragma unroll
    for (int i = 0; i < 4; ++i) {
        const int    nl = ty + 8 * i;
        const size_t nb = (size_t)b * NV + n0 + nl;
        *(float4*)(&in_lds[nl][  0 + j0]) = *(const float4*)(e2v   + nb * D + j0);
        *(float4*)(&in_lds[nl][128 + j0]) = *(const float4*)(nodes + nb * D + j0);
        *(float4*)(&in_lds[nl][256 + j0]) = *(const float4*)(gu + (size_t)b * D + j0);
    }
    __syncthreads();

    float acc[4][4] = {};
    #pragma unroll 4
    for (int k = 0; k < KN; ++k) {
        const float4 w = *(const float4*)(W_node + (size_t)k * D + j0);
        #pragma unroll
        for (int i = 0; i < 4; ++i) {
            const float x = in_lds[ty + 8 * i][k];
            acc[i][0] += x * w.x;
            acc[i][1] += x * w.y;
            acc[i][2] += x * w.z;
            acc[i][3] += x * w.w;
        }
    }

    const float4 bb = *(const float4*)(b_node + j0);
    float4 psum = make_float4(0.f, 0.f, 0.f, 0.f);
    #pragma unroll
    for (int i = 0; i < 4; ++i) {
        const int    nl = ty + 8 * i;
        const size_t nb = (size_t)b * NV + n0 + nl;
        float4 o;
        o.x = fmaxf(acc[i][0] + bb.x, 0.f);
        o.y = fmaxf(acc[i][1] + bb.y, 0.f);
        o.z = fmaxf(acc[i][2] + bb.z, 0.f);
        o.w = fmaxf(acc[i][3] + bb.w, 0.f);
        *(float4*)(nodes_p + nb * D + j0) = o;
        psum.x += o.x; psum.y += o.y; psum.z += o.z; psum.w += o.w;
    }

    __syncthreads();
    float* red = &in_lds[0][0];
    *(float4*)(red + ty * 128 + j0) = psum;
    __syncthreads();
    if (tid < 128) {
        float s = 0.f;
        #pragma unroll
        for (int t = 0; t < 8; ++t) s += red[t * 128 + tid];
        atomicAdd(&v2u[(size_t)b * D + tid], s);
    }
}

// ---------------------------------------------------------------------------
// Global block: relu(concat(e2u, v2u, u) @ W_g + b_g)
// ---------------------------------------------------------------------------
__global__ __launch_bounds__(128) void glob_kernel(
    const float* __restrict__ e2u,
    const float* __restrict__ v2u,
    const float* __restrict__ gu,
    const float* __restrict__ W_glob,     // (KG,D)
    const float* __restrict__ b_glob,
    float* __restrict__ glob_p)           // (B,D)
{
    __shared__ float gin[KG];
    const int b = blockIdx.x;
    const int j = threadIdx.x;

    gin[j      ] = e2u[(size_t)b * D + j];
    gin[j + 128] = v2u[(size_t)b * D + j];
    gin[j + 256] = gu [(size_t)b * D + j];
    __syncthreads();

    float acc = b_glob[j];
    #pragma unroll 4
    for (int k = 0; k < KG; ++k)
        acc += gin[k] * W_glob[(size_t)k * D + j];
    glob_p[(size_t)b * D + j] = fmaxf(acc, 0.f);
}

// ---------------------------------------------------------------------------
extern "C" void kernel_launch(void* const* d_in, const int* in_sizes, int n_in,
                              void* d_out, int out_size, void* d_ws, size_t ws_size,
                              hipStream_t stream) {
    const float* nodes      = (const float*)d_in[0];
    const float* edges      = (const float*)d_in[1];
    const float* gu         = (const float*)d_in[2];
    const int*   edge_rs    = (const int*)d_in[3];
    const int*   edge_masks = (const int*)d_in[4];
    const float* W_edge     = (const float*)d_in[5];
    const float* b_edge     = (const float*)d_in[6];
    const float* W_node     = (const float*)d_in[7];
    const float* b_node     = (const float*)d_in[8];
    const float* W_glob     = (const float*)d_in[9];
    const float* b_glob     = (const float*)d_in[10];

    float* out     = (float*)d_out;
    float* nodes_p = out;                                   // B*NV*D
    float* edges_p = out + (size_t)B * NV * D;              // B*NE*D
    float* glob_p  = edges_p + (size_t)B * NE * D;          // B*D

    float* e2v = (float*)d_ws;                              // B*NV*D
    float* e2u = e2v + (size_t)B * NV * D;                  // B*D
    float* v2u = e2u + (size_t)B * D;                       // B*D

    // zero the accumulators every call (ws is poisoned once, never restored)
    hipMemsetAsync(d_ws, 0, ((size_t)B * NV * D + 2 * (size_t)B * D) * sizeof(float), stream);

    dim3 eg(NE / 32, B);
    edge_kernel<<<eg, 256, 0, stream>>>(nodes, edges, gu, edge_rs, edge_masks,
                                        W_edge, b_edge, edges_p, e2v, e2u);
    dim3 ng(NV / 32, B);
    node_kernel<<<ng, 256, 0, stream>>>(nodes, gu, e2v, W_node, b_node,
                                        nodes_p, v2u);
    glob_kernel<<<B, 128, 0, stream>>>(e2u, v2u, gu, W_glob, b_glob, glob_p);
}

// Round 2
// 264.417 us; speedup vs baseline: 2.9201x; 2.9201x over previous
//
#include <hip/hip_runtime.h>

#define B  8
#define NV 4096
#define NE 32768
#define D  128
#define KE 512   // De + 2*Dv + Du
#define KN 384   // Dep + Dv + Du
#define KG 384   // Dep + Dvp + Du

using short8    = __attribute__((ext_vector_type(8))) short;
using f32x4     = __attribute__((ext_vector_type(4))) float;
using ushort4_t = __attribute__((ext_vector_type(4))) unsigned short;

__device__ inline unsigned short f2bf(float f) {
    unsigned u = __builtin_bit_cast(unsigned, f);
    u += 0x7FFFu + ((u >> 16) & 1u);          // RNE
    return (unsigned short)(u >> 16);
}

__device__ inline void store_bf4(unsigned short* base, int ldus, int row, int j, float4 v) {
    const int byte = (j * 2) ^ ((row & 7) << 4);          // XOR swizzle (G4 fix)
    ushort4_t p = { f2bf(v.x), f2bf(v.y), f2bf(v.z), f2bf(v.w) };
    *(ushort4_t*)(base + row * ldus + (byte >> 1)) = p;
}

// ---------------------------------------------------------------------------
// weight prep: Wt[n][k] = bf16(W[k][n])  (B-fragments become contiguous 16B)
// ---------------------------------------------------------------------------
__global__ __launch_bounds__(256) void prep_weights(
    const float* __restrict__ We, const float* __restrict__ Wn,
    unsigned short* __restrict__ WtE, unsigned short* __restrict__ WtN)
{
    const int idx = blockIdx.x * 256 + threadIdx.x;       // 0 .. 65535
    {   // edge: 128 x 512
        const int n = idx >> 9, k = idx & 511;
        WtE[idx] = f2bf(We[(size_t)k * D + n]);
    }
    if (idx < 128 * KN) {                                  // node: 128 x 384
        const int n = idx / KN, k = idx % KN;
        WtN[idx] = f2bf(Wn[(size_t)k * D + n]);
    }
}

// ---------------------------------------------------------------------------
// Edge block (MFMA): 64 edges/block, 256 thr = 4 waves, wave w -> cols [32w,32w+32)
// ---------------------------------------------------------------------------
__global__ __launch_bounds__(256, 2) void edge_kernel(
    const float* __restrict__ nodes,
    const float* __restrict__ edges,
    const float* __restrict__ gu,
    const int*   __restrict__ edge_rs,
    const int*   __restrict__ edge_masks,
    const unsigned short* __restrict__ WtE,   // (128,512) bf16, n-major
    const float* __restrict__ b_edge,
    float* __restrict__ edges_p,
    float* __restrict__ e2v,
    float* __restrict__ e2u)
{
    __shared__ unsigned short Ash[64 * KE];   // 64 KB bf16 concat tile (swizzled)
    __shared__ int recv_l[64];
    __shared__ int mask_l[64];

    const int b   = blockIdx.y;
    const int e0  = blockIdx.x * 64;
    const int tid = threadIdx.x;
    const int tx  = tid & 31;
    const int ty  = tid >> 5;
    const int j0  = tx * 4;

    if (tid < 64) {
        const size_t eb = (size_t)b * NE + e0 + tid;
        recv_l[tid] = ((const int2*)edge_rs)[eb].x;
        mask_l[tid] = edge_masks[eb];
    }

    const float4 uv = *(const float4*)(gu + (size_t)b * D + j0);
    #pragma unroll
    for (int i = 0; i < 8; ++i) {
        const int    row = ty + 8 * i;
        const size_t eb  = (size_t)b * NE + e0 + row;
        const int2   rs  = ((const int2*)edge_rs)[eb];
        const float4 ev  = *(const float4*)(edges + eb * (size_t)D + j0);
        const float4 rv  = *(const float4*)(nodes + ((size_t)b * NV + rs.x) * D + j0);
        const float4 sv  = *(const float4*)(nodes + ((size_t)b * NV + rs.y) * D + j0);
        store_bf4(Ash, KE, row,   0 + j0, ev);
        store_bf4(Ash, KE, row, 128 + j0, rv);
        store_bf4(Ash, KE, row, 256 + j0, sv);
        store_bf4(Ash, KE, row, 384 + j0, uv);
    }
    __syncthreads();

    const int lane = tid & 63;
    const int wv   = tid >> 6;
    const int lc   = lane & 15;   // col within 16-tile / row within A-tile
    const int lg   = lane >> 4;   // k-group

    f32x4 acc[4][2] = {};
    #pragma unroll 2
    for (int ks = 0; ks < KE / 32; ++ks) {
        const int kk = ks * 32 + lg * 8;
        short8 bfr[2], afr[4];
        #pragma unroll
        for (int nt = 0; nt < 2; ++nt) {
            const int col = wv * 32 + nt * 16 + lc;
            bfr[nt] = *(const short8*)(WtE + (size_t)col * KE + kk);
        }
        #pragma unroll
        for (int mt = 0; mt < 4; ++mt) {
            const int row  = mt * 16 + lc;
            const int byte = (kk * 2) ^ ((row & 7) << 4);
            afr[mt] = *(const short8*)(Ash + row * KE + (byte >> 1));
        }
        #pragma unroll
        for (int mt = 0; mt < 4; ++mt)
            #pragma unroll
            for (int nt = 0; nt < 2; ++nt)
                acc[mt][nt] = __builtin_amdgcn_mfma_f32_16x16x32_bf16(
                                  afr[mt], bfr[nt], acc[mt][nt], 0, 0, 0);
    }

    // epilogue: bias + relu, store, masked scatter, e2u reduce
    #pragma unroll
    for (int nt = 0; nt < 2; ++nt) {
        const int col  = wv * 32 + nt * 16 + lc;
        const float bias = b_edge[(size_t)b * 0 + col];
        float csum = 0.f;
        #pragma unroll
        for (int mt = 0; mt < 4; ++mt) {
            const int rbase = mt * 16 + lg * 4;
            #pragma unroll
            for (int r = 0; r < 4; ++r) {
                const int row = rbase + r;
                const float v = fmaxf(acc[mt][nt][r] + bias, 0.f);
                const size_t eb = (size_t)b * NE + e0 + row;
                edges_p[eb * D + col] = v;
                csum += v;
                if (mask_l[row])
                    atomicAdd(e2v + ((size_t)b * NV + recv_l[row]) * D + col, v);
            }
        }
        csum += __shfl_xor(csum, 16);
        csum += __shfl_xor(csum, 32);
        if (lg == 0) atomicAdd(e2u + (size_t)b * D + col, csum);
    }
}

// ---------------------------------------------------------------------------
// Node block (MFMA): 64 nodes/block, K = 384
// ---------------------------------------------------------------------------
__global__ __launch_bounds__(256, 3) void node_kernel(
    const float* __restrict__ nodes,
    const float* __restrict__ gu,
    const float* __restrict__ e2v,
    const unsigned short* __restrict__ WtN,   // (128,384) bf16, n-major
    const float* __restrict__ b_node,
    float* __restrict__ nodes_p,
    float* __restrict__ v2u)
{
    __shared__ unsigned short Ash[64 * KN];   // 48 KB

    const int b   = blockIdx.y;
    const int n0  = blockIdx.x * 64;
    const int tid = threadIdx.x;
    const int tx  = tid & 31;
    const int ty  = tid >> 5;
    const int j0  = tx * 4;

    const float4 uv = *(const float4*)(gu + (size_t)b * D + j0);
    #pragma unroll
    for (int i = 0; i < 8; ++i) {
        const int    row = ty + 8 * i;
        const size_t nb  = (size_t)b * NV + n0 + row;
        const float4 av  = *(const float4*)(e2v   + nb * (size_t)D + j0);
        const float4 nv  = *(const float4*)(nodes + nb * (size_t)D + j0);
        store_bf4(Ash, KN, row,   0 + j0, av);
        store_bf4(Ash, KN, row, 128 + j0, nv);
        store_bf4(Ash, KN, row, 256 + j0, uv);
    }
    __syncthreads();

    const int lane = tid & 63;
    const int wv   = tid >> 6;
    const int lc   = lane & 15;
    const int lg   = lane >> 4;

    f32x4 acc[4][2] = {};
    #pragma unroll 2
    for (int ks = 0; ks < KN / 32; ++ks) {
        const int kk = ks * 32 + lg * 8;
        short8 bfr[2], afr[4];
        #pragma unroll
        for (int nt = 0; nt < 2; ++nt) {
            const int col = wv * 32 + nt * 16 + lc;
            bfr[nt] = *(const short8*)(WtN + (size_t)col * KN + kk);
        }
        #pragma unroll
        for (int mt = 0; mt < 4; ++mt) {
            const int row  = mt * 16 + lc;
            const int byte = (kk * 2) ^ ((row & 7) << 4);
            afr[mt] = *(const short8*)(Ash + row * KN + (byte >> 1));
        }
        #pragma unroll
        for (int mt = 0; mt < 4; ++mt)
            #pragma unroll
            for (int nt = 0; nt < 2; ++nt)
                acc[mt][nt] = __builtin_amdgcn_mfma_f32_16x16x32_bf16(
                                  afr[mt], bfr[nt], acc[mt][nt], 0, 0, 0);
    }

    #pragma unroll
    for (int nt = 0; nt < 2; ++nt) {
        const int col  = wv * 32 + nt * 16 + lc;
        const float bias = b_node[col];
        float csum = 0.f;
        #pragma unroll
        for (int mt = 0; mt < 4; ++mt) {
            const int rbase = mt * 16 + lg * 4;
            #pragma unroll
            for (int r = 0; r < 4; ++r) {
                const int row = rbase + r;
                const float v = fmaxf(acc[mt][nt][r] + bias, 0.f);
                const size_t nb = (size_t)b * NV + n0 + row;
                nodes_p[nb * D + col] = v;
                csum += v;
            }
        }
        csum += __shfl_xor(csum, 16);
        csum += __shfl_xor(csum, 32);
        if (lg == 0) atomicAdd(v2u + (size_t)b * D + col, csum);
    }
}

// ---------------------------------------------------------------------------
// Global block: relu(concat(e2u, v2u, u) @ W_g + b_g)  (fp32, tiny)
// ---------------------------------------------------------------------------
__global__ __launch_bounds__(128) void glob_kernel(
    const float* __restrict__ e2u,
    const float* __restrict__ v2u,
    const float* __restrict__ gu,
    const float* __restrict__ W_glob,
    const float* __restrict__ b_glob,
    float* __restrict__ glob_p)
{
    __shared__ float gin[KG];
    const int b = blockIdx.x;
    const int j = threadIdx.x;

    gin[j      ] = e2u[(size_t)b * D + j];
    gin[j + 128] = v2u[(size_t)b * D + j];
    gin[j + 256] = gu [(size_t)b * D + j];
    __syncthreads();

    float acc = b_glob[j];
    #pragma unroll 4
    for (int k = 0; k < KG; ++k)
        acc += gin[k] * W_glob[(size_t)k * D + j];
    glob_p[(size_t)b * D + j] = fmaxf(acc, 0.f);
}

// ---------------------------------------------------------------------------
extern "C" void kernel_launch(void* const* d_in, const int* in_sizes, int n_in,
                              void* d_out, int out_size, void* d_ws, size_t ws_size,
                              hipStream_t stream) {
    const float* nodes      = (const float*)d_in[0];
    const float* edges      = (const float*)d_in[1];
    const float* gu         = (const float*)d_in[2];
    const int*   edge_rs    = (const int*)d_in[3];
    const int*   edge_masks = (const int*)d_in[4];
    const float* W_edge     = (const float*)d_in[5];
    const float* b_edge     = (const float*)d_in[6];
    const float* W_node     = (const float*)d_in[7];
    const float* b_node     = (const float*)d_in[8];
    const float* W_glob     = (const float*)d_in[9];
    const float* b_glob     = (const float*)d_in[10];

    float* out     = (float*)d_out;
    float* nodes_p = out;
    float* edges_p = out + (size_t)B * NV * D;
    float* glob_p  = edges_p + (size_t)B * NE * D;

    float* e2v = (float*)d_ws;                        // B*NV*D fp32
    float* e2u = e2v + (size_t)B * NV * D;            // B*D
    float* v2u = e2u + (size_t)B * D;                 // B*D
    unsigned short* WtE = (unsigned short*)(v2u + (size_t)B * D);  // 128*512 bf16
    unsigned short* WtN = WtE + 128 * KE;                          // 128*384 bf16

    hipMemsetAsync(d_ws, 0, ((size_t)B * NV * D + 2 * (size_t)B * D) * sizeof(float), stream);
    prep_weights<<<(128 * KE) / 256, 256, 0, stream>>>(W_edge, W_node, WtE, WtN);

    dim3 eg(NE / 64, B);
    edge_kernel<<<eg, 256, 0, stream>>>(nodes, edges, gu, edge_rs, edge_masks,
                                        WtE, b_edge, edges_p, e2v, e2u);
    dim3 ng(NV / 64, B);
    node_kernel<<<ng, 256, 0, stream>>>(nodes, gu, e2v, WtN, b_node, nodes_p, v2u);
    glob_kernel<<<B, 128, 0, stream>>>(e2u, v2u, gu, W_glob, b_glob, glob_p);
}